// Round 6
// baseline (196.117 us; speedup 1.0000x reference)
//
#include <hip/hip_runtime.h>
#include <stdint.h>

typedef int   v4i __attribute__((ext_vector_type(4)));
typedef float v4f __attribute__((ext_vector_type(4)));

// xt layout: [n][hp=58][wp=66][ci=128] int8, zero-padded (hp-1,wp-1 are src coords)
#define XT_H_STRIDE (66*128)          // 8448
#define XT_N_STRIDE (58*66*128)       // 489984
#define XT_BYTES    (32*58*66*128)    // 15,679,488
#define WQ_BYTES    (256*1152)        // 294,912

__device__ __forceinline__ void gload16(const void* g, void* l) {
  __builtin_amdgcn_global_load_lds(
      (const __attribute__((address_space(1))) void*)g,
      (__attribute__((address_space(3))) void*)l, 16, 0, 0);
}

// ---------------- x transform: fp32 NCHW -> int8 [n][hp][wp][ci] ----------------
// Coalesced both sides via LDS transpose. Unchanged (proven).
__global__ __launch_bounds__(256) void xform_x(const float* __restrict__ x,
                                               char* __restrict__ xt) {
  __shared__ int LB[56 * 33];          // [w][32 ci-dwords + 1 pad]
  int bid = blockIdx.x;                // 32*58
  int n  = bid / 58;
  int hp = bid - n * 58;
  int t  = threadIdx.x;
  int srch = hp - 1;
  bool rowok = (srch >= 0) && (srch < 56);
  char* dstrow = xt + (size_t)n * XT_N_STRIDE + (size_t)hp * XT_H_STRIDE;

  if (rowok) {
    const float* rb = x + ((size_t)(n * 128) * 56 + srch) * 56;   // + ci*3136 + w
#pragma unroll
    for (int u0 = 0; u0 < 2; ++u0) {
      int u  = t + u0 * 256;
      int wb = u & 15;
      int cb = u >> 4;
      int w0 = wb * 4, ci0 = cb * 4;
      if (w0 < 56) {
        int dw[4] = {0, 0, 0, 0};
#pragma unroll
        for (int i = 0; i < 4; ++i) {
          v4f f = *(const v4f*)(rb + (size_t)(ci0 + i) * 3136 + w0);
#pragma unroll
          for (int j = 0; j < 4; ++j)
            dw[j] |= (((int)f[j]) & 255) << (8 * i);
        }
#pragma unroll
        for (int j = 0; j < 4; ++j)
          LB[(w0 + j) * 33 + cb] = dw[j];
      }
    }
    __syncthreads();
    for (int c = t; c < 528; c += 256) {
      int wp  = c >> 3;
      int cio = c & 7;
      int srw = wp - 1;
      v4i v = {0, 0, 0, 0};
      if (srw >= 0 && srw < 56) {
#pragma unroll
        for (int k = 0; k < 4; ++k) v[k] = LB[srw * 33 + cio * 4 + k];
      }
      *(v4i*)(dstrow + c * 16) = v;
    }
  } else {
    v4i z = {0, 0, 0, 0};
    for (int c = t; c < 528; c += 256) *(v4i*)(dstrow + c * 16) = z;
  }
}

// ---------------- w transform: OIHW fp32 -> int8 wq3 + scale ----------------
// R9 layout: [kt18][mhalf2][chunk4][co128][16] int8. Per (kt, mhalf) the 8KB
// panel is contiguous AND in exactly the byte order the GEMM's DMA writes LDS
// (linear lane*16) and the MFMA A-frag ds_reads consume (lane-contiguous,
// conflict-free, no swizzle anywhere on the A side).
__global__ __launch_bounds__(256) void xform_w(const float* __restrict__ wsrc,
                                               const int* __restrict__ Aq,
                                               const int* __restrict__ Nq,
                                               char* __restrict__ wq3,
                                               float* __restrict__ scale) {
  int idx = blockIdx.x * 256 + threadIdx.x;    // 294912
  int co = idx / 1152;
  int k  = idx - co * 1152;          // K index: g*128 + ci
  int g  = k >> 7;
  int ci = k & 127;
  int kh = g / 3;
  int kw = g - 3 * kh;
  float f = wsrc[(size_t)(co * 128 + ci) * 9 + kh * 3 + kw];
  int kt    = k >> 6;                // 0..17 (BK=64)
  int mhalf = co >> 7;
  int chunk = (k >> 4) & 3;          // 16B k-chunk within BK=64
  int row   = co & 127;
  int col   = k & 15;
  wq3[(((kt * 2 + mhalf) * 4 + chunk) * 128 + row) * 16 + col] = (signed char)(int)f;
  if (idx < 256) {
    scale[idx] = (float)Aq[idx] * exp2f(-(float)Nq[idx]);   // exact: A < 2^15
  }
}

// ---------------- GEMM: C[co][n,h,w] = sum_k wq[co][k] * xt[...] ----------------
// R9: m201-style DMA pipeline for A.
//   R8 post-mortem: register pipeline WAS materialized (VGPR 76 = 2x32 operands
//   + addr; acc AGPRs reported separately) yet MfmaUtil stuck at 22%. Residual
//   suspects: per-wave redundant A loads choking the 64B/cy L1 pipe (48KB/CU
//   per window) and A L2/L3 latency > 1-window prefetch distance.
//   Fix both: A staged by global_load_lds DMA (8KB/block-kt, no redundancy, no
//   VGPR return) into a 3-buffer LDS ring, DMA issued TWO windows ahead,
//   counted s_waitcnt vmcnt(2) + single raw s_barrier per window (pipe never
//   drains in steady state). A panel layout makes DMA dest linear and A
//   ds_reads lane-contiguous (conflict-free, swizzle-free). B unchanged:
//   persistent swizzled Bp + 1-deep register prefetch (0 conflicts, proven).
// 128x128 tile, 4 waves (2x2), 4x4 frags of mfma_i32_16x16x64_i8, BK=64.
// LDS: Bp 33792 + As 3x8192 = 58368 -> 2 blocks/CU. Grid 1792.
__global__ __launch_bounds__(256, 2) void qconv_gemm(
    const char* __restrict__ xt, const char* __restrict__ wq3,
    const float* __restrict__ bias, const float* __restrict__ scale,
    const int* __restrict__ pmin, const int* __restrict__ pmax,
    float* __restrict__ out) {
  __shared__ __align__(16) char Bp[4 * 8448];   // 33792 B: 4 xt rows, swizzled chunks
  __shared__ __align__(16) char As[3][8192];    // ring: [chunk4][co128][16]

  // XCD-aware swizzle: mt pair (shared B rows) + contiguous nt range per XCD.
  int bid = blockIdx.x;        // 1792
  int xcd = bid & 7;
  int q   = bid >> 3;
  int mt  = q & 1;
  int nt  = xcd * 112 + (q >> 1);
  int n   = nt / 28;
  int ht  = nt - n * 28;
  int h0  = ht * 2;
  int m0  = mt * 128;

  int t  = threadIdx.x;
  int wv = t >> 6;
  int ln = t & 63;
  int quad = ln >> 4;
  int l16  = ln & 15;
  int wm = wv & 1, wn = wv >> 1;

  const char* xb    = xt + (size_t)n * XT_N_STRIDE + (size_t)h0 * XT_H_STRIDE;
  const char* wbase = wq3 + mt * 8192;          // + kt*16384: this block's 8KB panels

  // ---- stage Bp (once): slot s holds global chunk (row, w, cq^(w&7)) ----
  for (int it = 0; it < 9; ++it) {
    int s = t + it * 256;
    if (s < 2112) {                     // tail: only wave 0, full 64 lanes
      int row = s / 528;
      int rr  = s - row * 528;
      int w   = rr >> 3;
      int cq  = rr & 7;
      gload16(xb + row * XT_H_STRIDE + w * 128 + ((cq ^ (w & 7)) << 4),
              Bp + it * 4096 + wv * 1024);
    }
  }
  // ---- DMA A panels kt=0 -> As[0], kt=1 -> As[1] (linear both sides) ----
#pragma unroll
  for (int kk = 0; kk < 2; ++kk) {
    const char* src = wbase + kk * 16384;
    gload16(src + t * 16,        As[kk] + wv * 1024);
    gload16(src + 4096 + t * 16, As[kk] + 4096 + wv * 1024);
  }
  // Bp + As[0] landed (leave kt=1's 2 newest in flight), then raw barrier.
  asm volatile("s_waitcnt vmcnt(2)" ::: "memory");
  asm volatile("s_barrier" ::: "memory");

  // ---- B frags for kt=0 (g=0: kh=0, kw=0, p=0); landed check = in-loop lgkmcnt ----
  v4i a[4], b[4], bn[4];
  {
    const char* bb = Bp + wn * XT_H_STRIDE + l16 * 128 + ((quad ^ (l16 & 7)) << 4);
#pragma unroll
    for (int j = 0; j < 4; ++j)
      b[j] = *(const v4i*)(bb + j * 2048);
  }

  v4i acc[4][4];
#pragma unroll
  for (int i = 0; i < 4; ++i)
#pragma unroll
    for (int j = 0; j < 4; ++j) {
      v4i z = {0, 0, 0, 0};
      acc[i][j] = z;
    }

#pragma unroll
  for (int kt = 0; kt < 18; ++kt) {
    const int p = kt % 3;

    // issue DMA for kt+2 into the buffer freed at the last barrier.
    if (kt < 16) {
      const char* src = wbase + (kt + 2) * 16384;
      char* dst = As[(kt + 2) % 3];
      gload16(src + t * 16,        dst + wv * 1024);
      gload16(src + 4096 + t * 16, dst + 4096 + wv * 1024);
    }

    // A frags from As[p]: addr = quad*2048 + row*16, rows lane-contiguous.
    const char* ab = As[p] + quad * 2048 + (wm * 64 + l16) * 16;
#pragma unroll
    for (int i = 0; i < 4; ++i)
      a[i] = *(const v4i*)(ab + i * 256);

    // a[] this window + bn[] issued last window must land; pin MFMAs (rule 18).
    __builtin_amdgcn_sched_barrier(0);
    asm volatile("s_waitcnt lgkmcnt(0)" ::: "memory");
    __builtin_amdgcn_sched_barrier(0);

    __builtin_amdgcn_s_setprio(1);
#pragma unroll
    for (int i = 0; i < 4; ++i)
#pragma unroll
      for (int j = 0; j < 4; ++j)
        acc[i][j] = __builtin_amdgcn_mfma_i32_16x16x64_i8(a[i], b[j], acc[i][j], 0, 0, 0);
    __builtin_amdgcn_s_setprio(0);

    if (kt < 17) {
      // B frags for kt+1 from persistent Bp (always valid; covered by next lgkmcnt).
      const int kn  = kt + 1;
      const int pn  = kn & 1;
      const int gn  = kn >> 1;
      const int khn = gn / 3;
      const int kwn = gn - 3 * khn;
      int bswzn = (((pn << 2) + quad) ^ ((l16 + kwn) & 7)) << 4;
      const char* bbn = Bp + (wn + khn) * XT_H_STRIDE + (l16 + kwn) * 128 + bswzn;
#pragma unroll
      for (int j = 0; j < 4; ++j)
        bn[j] = *(const v4i*)(bbn + j * 2048);

      // single barrier per window: DMA(kt+1) landed (leave kt+2's pair in
      // flight); all waves done reading As[p] -> its slot is free for reuse.
      __builtin_amdgcn_sched_barrier(0);
      if (kt < 16) {
        asm volatile("s_waitcnt vmcnt(2)" ::: "memory");
      } else {
        asm volatile("s_waitcnt vmcnt(0)" ::: "memory");   // kt=16: drain DMA(17)
      }
      asm volatile("s_barrier" ::: "memory");

#pragma unroll
      for (int u = 0; u < 4; ++u) b[u] = bn[u];   // renamed by full unroll
    }
  }

  // epilogue: co = m0 + wm*64 + i*16 + quad*4 + r ; spatial = wn*64 + j*16 + l16
  float mn = (float)pmin[0];
  float mx = (float)pmax[0];
#pragma unroll
  for (int i = 0; i < 4; ++i) {
    int co_b = m0 + wm * 64 + i * 16 + quad * 4;
#pragma unroll
    for (int r = 0; r < 4; ++r) {
      int co = co_b + r;
      float bs = bias[co];
      float sc = scale[co];
#pragma unroll
      for (int j = 0; j < 4; ++j) {
        int sl = wn * 64 + j * 16 + l16;
        int w  = sl & 63;
        int dh = sl >> 6;
        if (w < 56) {
          float f = (float)acc[i][j][r] + bs;
          f = rintf(f * sc);                 // half-to-even, matches np.round
          f = fminf(fmaxf(f, mn), mx);
          out[(((size_t)n * 256 + co) * 56 + (h0 + dh)) * 56 + w] = f;
        }
      }
    }
  }
}

extern "C" void kernel_launch(void* const* d_in, const int* in_sizes, int n_in,
                              void* d_out, int out_size, void* d_ws, size_t ws_size,
                              hipStream_t stream) {
  const float* x  = (const float*)d_in[0];
  const float* w  = (const float*)d_in[1];
  const float* b  = (const float*)d_in[2];
  const int*   Aq = (const int*)d_in[3];
  const int*   Nq = (const int*)d_in[4];
  const int*   mn = (const int*)d_in[5];
  const int*   mx = (const int*)d_in[6];
  float* out = (float*)d_out;

  char*  xt    = (char*)d_ws;                  // 15,679,488 B
  char*  wq3   = xt + XT_BYTES;                // 294,912 B (kt/mhalf/chunk layout)
  float* scale = (float*)(wq3 + WQ_BYTES);     // 1 KiB

  hipLaunchKernelGGL(xform_x, dim3(32 * 58), dim3(256), 0, stream, x, xt);
  hipLaunchKernelGGL(xform_w, dim3(1152), dim3(256), 0, stream, w, Aq, Nq, wq3, scale);
  hipLaunchKernelGGL(qconv_gemm, dim3(1792), dim3(256), 0, stream,
                     xt, wq3, b, scale, mn, mx, out);
}